// Round 1
// baseline (639.732 us; speedup 1.0000x reference)
//
#include <hip/hip_runtime.h>

// ---------------------------------------------------------------------------
// SimpleGCN: 2x GCNConv (self-loops, symmetric norm) + mean pool + MLP head
// N=100000 nodes, E=1.6M edges, IN=128, HID=64, G=128 graphs, NCLS=10
//
// Plan:
//  1. deg[c] = 1 + sum(ew at col c)   (atomics), cnt[c] = in-degree (int)
//  2. dinv = 1/sqrt(deg)
//  3. exclusive scan of cnt -> offs (3-kernel scan), cursor = offs
//  4. scatter edges into CSR-by-destination: csr_src, csr_nrm (built ONCE,
//     used by both conv layers since norm depends only on edges/weights)
//  5. h = x @ W1   (tiled f32 matmul, LDS, 4x4 register tile)
//  6. o = relu(aggregate(h) + b1)     (one wave per node, lane = channel)
//  7. h = o @ W2
//  8. o = relu(aggregate(h) + b2)
//  9. per-graph mean pool (binary search on sorted batch) + fused MLP head
// ---------------------------------------------------------------------------

#define TPB 256

__device__ __forceinline__ int lower_bound_i(const int* __restrict__ a, int n, int key) {
    int lo = 0, hi = n;
    while (lo < hi) {
        int mid = (lo + hi) >> 1;
        if (a[mid] < key) lo = mid + 1; else hi = mid;
    }
    return lo;
}

// --- 1. init -----------------------------------------------------------------
__global__ void k_init(float* __restrict__ deg, int* __restrict__ cnt, int n) {
    int i = blockIdx.x * TPB + threadIdx.x;
    if (i < n) { deg[i] = 1.0f; cnt[i] = 0; }  // self-loop weight 1
}

__global__ void k_edge_deg(const int* __restrict__ col, const float* __restrict__ ew,
                           float* __restrict__ deg, int* __restrict__ cnt, int E) {
    int e = blockIdx.x * TPB + threadIdx.x;
    if (e < E) {
        int c = col[e];
        atomicAdd(&deg[c], ew[e]);
        atomicAdd(&cnt[c], 1);
    }
}

// --- 2. dinv -----------------------------------------------------------------
__global__ void k_dinv(const float* __restrict__ deg, float* __restrict__ dinv, int n) {
    int i = blockIdx.x * TPB + threadIdx.x;
    if (i < n) dinv[i] = 1.0f / sqrtf(deg[i]);  // deg >= 1 always (self-loop)
}

// --- 3. scan (1024 elems per block) -----------------------------------------
__global__ void k_scan_partial(const int* __restrict__ cnt, int* __restrict__ bsums, int n) {
    __shared__ int red[4];
    int b = blockIdx.x, t = threadIdx.x;
    int base = b * 1024;
    int s = 0;
#pragma unroll
    for (int i = 0; i < 4; i++) {
        int idx = base + t + i * TPB;
        if (idx < n) s += cnt[idx];
    }
#pragma unroll
    for (int off = 32; off > 0; off >>= 1) s += __shfl_down(s, off);
    if ((t & 63) == 0) red[t >> 6] = s;
    __syncthreads();
    if (t == 0) bsums[b] = red[0] + red[1] + red[2] + red[3];
}

__global__ void k_scan_bsums(int* __restrict__ bsums, int nb) {
    // single block of 64 threads; chunked wave scan with carry
    int l = threadIdx.x;
    int carry = 0;
    for (int base = 0; base < nb; base += 64) {
        int i = base + l;
        int v = (i < nb) ? bsums[i] : 0;
        int orig = v;
#pragma unroll
        for (int off = 1; off < 64; off <<= 1) {
            int x = __shfl_up(v, off);
            if (l >= off) v += x;
        }
        if (i < nb) bsums[i] = v - orig + carry;  // exclusive + carry
        carry += __shfl(v, 63);
    }
}

__global__ void k_scan_final(const int* __restrict__ cnt, const int* __restrict__ boffs,
                             int* __restrict__ offs, int* __restrict__ cursor, int n) {
    __shared__ int ts[TPB];
    int b = blockIdx.x, t = threadIdx.x;
    int base = b * 1024 + 4 * t;
    int v[4]; int s = 0;
#pragma unroll
    for (int i = 0; i < 4; i++) {
        int idx = base + i;
        v[i] = (idx < n) ? cnt[idx] : 0;
        s += v[i];
    }
    ts[t] = s; __syncthreads();
    for (int off = 1; off < TPB; off <<= 1) {
        int x = (t >= off) ? ts[t - off] : 0;
        __syncthreads();
        ts[t] += x;
        __syncthreads();
    }
    int run = ts[t] - s + boffs[b];  // exclusive prefix for this thread's 4 elems
#pragma unroll
    for (int i = 0; i < 4; i++) {
        int idx = base + i;
        if (idx < n) { offs[idx] = run; cursor[idx] = run; }
        run += v[i];
    }
}

// --- 4. scatter into CSR -----------------------------------------------------
__global__ void k_scatter(const int* __restrict__ row, const int* __restrict__ col,
                          const float* __restrict__ ew, const float* __restrict__ dinv,
                          int* __restrict__ cursor, int* __restrict__ csr_src,
                          float* __restrict__ csr_nrm, int E) {
    int e = blockIdx.x * TPB + threadIdx.x;
    if (e < E) {
        int r = row[e], c = col[e];
        float nrm = dinv[r] * ew[e] * dinv[c];
        int pos = atomicAdd(&cursor[c], 1);
        csr_src[pos] = r;
        csr_nrm[pos] = nrm;
    }
}

// --- 5/7. matmul: H[n,64] = X[n,K] @ W[K,64] --------------------------------
// 64 rows x 64 cols per block. 256 threads, each computes a 4x4 register tile.
// X is staged to LDS transposed (k-major) in KS=64 chunks with an XOR quad
// swizzle to avoid bank conflicts on both the store and the b128 read.
template <int K>
__global__ __launch_bounds__(256) void k_matmul(const float* __restrict__ X,
                                                const float* __restrict__ W,
                                                float* __restrict__ H, int n) {
    constexpr int KS = 64;                    // k per stage
    __shared__ __align__(16) float Xs[KS * 68];   // [k][swizzled row quad]
    __shared__ __align__(16) float Ws[K * 64];    // [k][col]
    const int t = threadIdx.x;
    const int rowBase = blockIdx.x * 64;

    // load W whole (k-major already, coalesced float4)
#pragma unroll
    for (int i = t; i < K * 16; i += 256)
        reinterpret_cast<float4*>(Ws)[i] = reinterpret_cast<const float4*>(W)[i];

    const int cg = t & 15;        // col quad 0..15 -> cols 4cg..4cg+3
    const int rg = t >> 4;        // row quad 0..15 -> rows 4rg..4rg+3
    float acc[4][4] = {{0.f}};

    for (int k0 = 0; k0 < K; k0 += KS) {
        __syncthreads();
        // stage Xs: rows rowBase..+63, local k 0..KS-1, transposed + swizzled
        for (int i = t; i < 64 * (KS / 4); i += 256) {
            int r = i / (KS / 4);             // 0..63
            int q = i - r * (KS / 4);         // local quad 0..15
            int gr = rowBase + r;
            float4 v = make_float4(0.f, 0.f, 0.f, 0.f);
            if (gr < n) v = reinterpret_cast<const float4*>(X)[(size_t)gr * (K / 4) + (k0 / 4) + q];
            int g2 = (((r >> 2) ^ (q & 15)) << 2) + (r & 3);
            int kk = q * 4;
            Xs[(kk + 0) * 68 + g2] = v.x;
            Xs[(kk + 1) * 68 + g2] = v.y;
            Xs[(kk + 2) * 68 + g2] = v.z;
            Xs[(kk + 3) * 68 + g2] = v.w;
        }
        __syncthreads();
#pragma unroll 4
        for (int kk = 0; kk < KS; kk++) {
            const float4 xv = *reinterpret_cast<const float4*>(
                &Xs[kk * 68 + ((rg ^ ((kk >> 2) & 15)) << 2)]);
            const float4 wv = *reinterpret_cast<const float4*>(
                &Ws[(k0 + kk) * 64 + 4 * cg]);
            const float xa[4] = {xv.x, xv.y, xv.z, xv.w};
            const float wa[4] = {wv.x, wv.y, wv.z, wv.w};
#pragma unroll
            for (int i = 0; i < 4; i++)
#pragma unroll
                for (int j = 0; j < 4; j++)
                    acc[i][j] = fmaf(xa[i], wa[j], acc[i][j]);
        }
    }

#pragma unroll
    for (int i = 0; i < 4; i++) {
        int gr = rowBase + 4 * rg + i;
        if (gr < n) {
            float4 o = make_float4(acc[i][0], acc[i][1], acc[i][2], acc[i][3]);
            reinterpret_cast<float4*>(H)[(size_t)gr * 16 + cg] = o;
        }
    }
}

// --- 6/8. aggregate: out[c] = relu(sum_{e->c} nrm*h[src] + dinv^2*h[c] + b) --
// one wave per node, lane = channel (64 = HID). Coalesced 256B row gathers.
__global__ __launch_bounds__(256) void k_aggregate(
    const float* __restrict__ h, const int* __restrict__ offs,
    const int* __restrict__ cnt, const int* __restrict__ csr_src,
    const float* __restrict__ csr_nrm, const float* __restrict__ dinv,
    const float* __restrict__ bias, float* __restrict__ out, int n) {
    int lane = threadIdx.x & 63;
    int node = blockIdx.x * 4 + (threadIdx.x >> 6);
    if (node >= n) return;
    float di = dinv[node];
    float acc = h[(size_t)node * 64 + lane] * (di * di);  // self loop
    int s = offs[node];
    int e = s + cnt[node];
    for (int j = s; j < e; ++j) {
        int src = csr_src[j];
        float nr = csr_nrm[j];
        acc = fmaf(h[(size_t)src * 64 + lane], nr, acc);
    }
    float r = acc + bias[lane];
    out[(size_t)node * 64 + lane] = fmaxf(r, 0.0f);
}

// --- 9. mean pool per graph + fused MLP head --------------------------------
__global__ __launch_bounds__(1024) void k_pool_head(
    const float* __restrict__ h, const int* __restrict__ batch, int n,
    const float* __restrict__ Wc1, const float* __restrict__ bc1,
    const float* __restrict__ Wc2, const float* __restrict__ bc2,
    float* __restrict__ out) {
    const int g = blockIdx.x;
    const int t = threadIdx.x;
    const int lane = t & 63, w = t >> 6;   // 16 waves
    __shared__ float sums[16][64];
    __shared__ float pooled[64];
    __shared__ float z[32];

    int start = lower_bound_i(batch, n, g);
    int end   = lower_bound_i(batch, n, g + 1);

    float acc = 0.f;
    for (int i = start + w; i < end; i += 16)
        acc += h[(size_t)i * 64 + lane];
    sums[w][lane] = acc;
    __syncthreads();
    if (w == 0) {
        float v = 0.f;
#pragma unroll
        for (int k = 0; k < 16; k++) v += sums[k][lane];
        float c = (float)(end - start);
        pooled[lane] = v / fmaxf(c, 1.0f);
    }
    __syncthreads();
    if (t < 32) {
        float a = bc1[t];
        for (int k = 0; k < 64; k++) a = fmaf(pooled[k], Wc1[k * 32 + t], a);
        z[t] = fmaxf(a, 0.f);
    }
    __syncthreads();
    if (t < 10) {
        float a = bc2[t];
        for (int k = 0; k < 32; k++) a = fmaf(z[k], Wc2[k * 10 + t], a);
        out[g * 10 + t] = a;
    }
}

// ---------------------------------------------------------------------------
extern "C" void kernel_launch(void* const* d_in, const int* in_sizes, int n_in,
                              void* d_out, int out_size, void* d_ws, size_t ws_size,
                              hipStream_t stream) {
    const float* x    = (const float*)d_in[0];
    const int*   ei   = (const int*)d_in[1];
    const float* ew   = (const float*)d_in[2];
    const int*   bat  = (const int*)d_in[3];
    const float* W1   = (const float*)d_in[4];
    const float* b1   = (const float*)d_in[5];
    const float* W2   = (const float*)d_in[6];
    const float* b2   = (const float*)d_in[7];
    const float* Wc1  = (const float*)d_in[8];
    const float* bc1  = (const float*)d_in[9];
    const float* Wc2  = (const float*)d_in[10];
    const float* bc2  = (const float*)d_in[11];
    float* out = (float*)d_out;

    const int N = in_sizes[0] / 128;
    const int E = in_sizes[2];
    const int G = out_size / 10;

    const int* row = ei;
    const int* col = ei + E;

    // workspace carve-up (256B aligned slices); total ~66 MB
    char* p = (char*)d_ws;
    auto alloc = [&](size_t bytes) -> void* {
        void* r = (void*)p;
        p += (bytes + 255) & ~(size_t)255;
        return r;
    };
    float* deg    = (float*)alloc((size_t)N * 4);
    float* dinv   = (float*)alloc((size_t)N * 4);
    int*   cnt    = (int*)  alloc((size_t)N * 4);
    int*   offs   = (int*)  alloc((size_t)N * 4);
    int*   cursor = (int*)  alloc((size_t)N * 4);
    int*   bsums  = (int*)  alloc(8192);
    int*   csr_src= (int*)  alloc((size_t)E * 4);
    float* csr_nrm= (float*)alloc((size_t)E * 4);
    float* h      = (float*)alloc((size_t)N * 64 * 4);
    float* o      = (float*)alloc((size_t)N * 64 * 4);

    const int gb_n = (N + TPB - 1) / TPB;
    const int gb_e = (E + TPB - 1) / TPB;
    const int NB   = (N + 1023) / 1024;

    k_init<<<gb_n, TPB, 0, stream>>>(deg, cnt, N);
    k_edge_deg<<<gb_e, TPB, 0, stream>>>(col, ew, deg, cnt, E);
    k_dinv<<<gb_n, TPB, 0, stream>>>(deg, dinv, N);
    k_scan_partial<<<NB, TPB, 0, stream>>>(cnt, bsums, N);
    k_scan_bsums<<<1, 64, 0, stream>>>(bsums, NB);
    k_scan_final<<<NB, TPB, 0, stream>>>(cnt, bsums, offs, cursor, N);
    k_scatter<<<gb_e, TPB, 0, stream>>>(row, col, ew, dinv, cursor, csr_src, csr_nrm, E);

    const int gb_mm = (N + 63) / 64;
    const int gb_ag = (N + 3) / 4;

    // layer 1
    k_matmul<128><<<gb_mm, 256, 0, stream>>>(x, W1, h, N);
    k_aggregate<<<gb_ag, 256, 0, stream>>>(h, offs, cnt, csr_src, csr_nrm, dinv, b1, o, N);
    // layer 2
    k_matmul<64><<<gb_mm, 256, 0, stream>>>(o, W2, h, N);
    k_aggregate<<<gb_ag, 256, 0, stream>>>(h, offs, cnt, csr_src, csr_nrm, dinv, b2, o, N);
    // pool + head
    k_pool_head<<<G, 1024, 0, stream>>>(o, bat, N, Wc1, bc1, Wc2, bc2, out);
}

// Round 2
// 463.130 us; speedup vs baseline: 1.3813x; 1.3813x over previous
//
#include <hip/hip_runtime.h>

// ---------------------------------------------------------------------------
// SimpleGCN: 2x GCNConv (self-loops, symmetric norm) + mean pool + MLP head
// N=100000 nodes, E=1.6M edges, IN=128, HID=64, G=128 graphs, NCLS=10
//
// Round 1 change: k_aggregate was latency-bound (154us, VALUBusy 16%,
// HBM 18%). Unroll edge loop x8 with independent accumulators -> 8 gathers
// in flight per wave; pack (src,nrm) into int2 for single 8B edge loads.
// ---------------------------------------------------------------------------

#define TPB 256

__device__ __forceinline__ int lower_bound_i(const int* __restrict__ a, int n, int key) {
    int lo = 0, hi = n;
    while (lo < hi) {
        int mid = (lo + hi) >> 1;
        if (a[mid] < key) lo = mid + 1; else hi = mid;
    }
    return lo;
}

// --- 1. init -----------------------------------------------------------------
__global__ void k_init(float* __restrict__ deg, int* __restrict__ cnt, int n) {
    int i = blockIdx.x * TPB + threadIdx.x;
    if (i < n) { deg[i] = 1.0f; cnt[i] = 0; }  // self-loop weight 1
}

__global__ void k_edge_deg(const int* __restrict__ col, const float* __restrict__ ew,
                           float* __restrict__ deg, int* __restrict__ cnt, int E) {
    int e = blockIdx.x * TPB + threadIdx.x;
    if (e < E) {
        int c = col[e];
        atomicAdd(&deg[c], ew[e]);
        atomicAdd(&cnt[c], 1);
    }
}

// --- 2. dinv -----------------------------------------------------------------
__global__ void k_dinv(const float* __restrict__ deg, float* __restrict__ dinv, int n) {
    int i = blockIdx.x * TPB + threadIdx.x;
    if (i < n) dinv[i] = 1.0f / sqrtf(deg[i]);  // deg >= 1 always (self-loop)
}

// --- 3. scan (1024 elems per block) -----------------------------------------
__global__ void k_scan_partial(const int* __restrict__ cnt, int* __restrict__ bsums, int n) {
    __shared__ int red[4];
    int b = blockIdx.x, t = threadIdx.x;
    int base = b * 1024;
    int s = 0;
#pragma unroll
    for (int i = 0; i < 4; i++) {
        int idx = base + t + i * TPB;
        if (idx < n) s += cnt[idx];
    }
#pragma unroll
    for (int off = 32; off > 0; off >>= 1) s += __shfl_down(s, off);
    if ((t & 63) == 0) red[t >> 6] = s;
    __syncthreads();
    if (t == 0) bsums[b] = red[0] + red[1] + red[2] + red[3];
}

__global__ void k_scan_bsums(int* __restrict__ bsums, int nb) {
    // single block of 64 threads; chunked wave scan with carry
    int l = threadIdx.x;
    int carry = 0;
    for (int base = 0; base < nb; base += 64) {
        int i = base + l;
        int v = (i < nb) ? bsums[i] : 0;
        int orig = v;
#pragma unroll
        for (int off = 1; off < 64; off <<= 1) {
            int x = __shfl_up(v, off);
            if (l >= off) v += x;
        }
        if (i < nb) bsums[i] = v - orig + carry;  // exclusive + carry
        carry += __shfl(v, 63);
    }
}

__global__ void k_scan_final(const int* __restrict__ cnt, const int* __restrict__ boffs,
                             int* __restrict__ offs, int* __restrict__ cursor, int n) {
    __shared__ int ts[TPB];
    int b = blockIdx.x, t = threadIdx.x;
    int base = b * 1024 + 4 * t;
    int v[4]; int s = 0;
#pragma unroll
    for (int i = 0; i < 4; i++) {
        int idx = base + i;
        v[i] = (idx < n) ? cnt[idx] : 0;
        s += v[i];
    }
    ts[t] = s; __syncthreads();
    for (int off = 1; off < TPB; off <<= 1) {
        int x = (t >= off) ? ts[t - off] : 0;
        __syncthreads();
        ts[t] += x;
        __syncthreads();
    }
    int run = ts[t] - s + boffs[b];  // exclusive prefix for this thread's 4 elems
#pragma unroll
    for (int i = 0; i < 4; i++) {
        int idx = base + i;
        if (idx < n) { offs[idx] = run; cursor[idx] = run; }
        run += v[i];
    }
}

// --- 4. scatter into CSR (packed int2: {src, nrm-as-bits}) -------------------
__global__ void k_scatter(const int* __restrict__ row, const int* __restrict__ col,
                          const float* __restrict__ ew, const float* __restrict__ dinv,
                          int* __restrict__ cursor, int2* __restrict__ csr, int E) {
    int e = blockIdx.x * TPB + threadIdx.x;
    if (e < E) {
        int r = row[e], c = col[e];
        float nrm = dinv[r] * ew[e] * dinv[c];
        int pos = atomicAdd(&cursor[c], 1);
        csr[pos] = make_int2(r, __float_as_int(nrm));
    }
}

// --- 5/7. matmul: H[n,64] = X[n,K] @ W[K,64] --------------------------------
template <int K>
__global__ __launch_bounds__(256) void k_matmul(const float* __restrict__ X,
                                                const float* __restrict__ W,
                                                float* __restrict__ H, int n) {
    constexpr int KS = 64;                    // k per stage
    __shared__ __align__(16) float Xs[KS * 68];   // [k][swizzled row quad]
    __shared__ __align__(16) float Ws[K * 64];    // [k][col]
    const int t = threadIdx.x;
    const int rowBase = blockIdx.x * 64;

    // load W whole (k-major already, coalesced float4)
#pragma unroll
    for (int i = t; i < K * 16; i += 256)
        reinterpret_cast<float4*>(Ws)[i] = reinterpret_cast<const float4*>(W)[i];

    const int cg = t & 15;        // col quad 0..15 -> cols 4cg..4cg+3
    const int rg = t >> 4;        // row quad 0..15 -> rows 4rg..4rg+3
    float acc[4][4] = {{0.f}};

    for (int k0 = 0; k0 < K; k0 += KS) {
        __syncthreads();
        // stage Xs: rows rowBase..+63, local k 0..KS-1, transposed + swizzled
        for (int i = t; i < 64 * (KS / 4); i += 256) {
            int r = i / (KS / 4);             // 0..63
            int q = i - r * (KS / 4);         // local quad 0..15
            int gr = rowBase + r;
            float4 v = make_float4(0.f, 0.f, 0.f, 0.f);
            if (gr < n) v = reinterpret_cast<const float4*>(X)[(size_t)gr * (K / 4) + (k0 / 4) + q];
            int g2 = (((r >> 2) ^ (q & 15)) << 2) + (r & 3);
            int kk = q * 4;
            Xs[(kk + 0) * 68 + g2] = v.x;
            Xs[(kk + 1) * 68 + g2] = v.y;
            Xs[(kk + 2) * 68 + g2] = v.z;
            Xs[(kk + 3) * 68 + g2] = v.w;
        }
        __syncthreads();
#pragma unroll 4
        for (int kk = 0; kk < KS; kk++) {
            const float4 xv = *reinterpret_cast<const float4*>(
                &Xs[kk * 68 + ((rg ^ ((kk >> 2) & 15)) << 2)]);
            const float4 wv = *reinterpret_cast<const float4*>(
                &Ws[(k0 + kk) * 64 + 4 * cg]);
            const float xa[4] = {xv.x, xv.y, xv.z, xv.w};
            const float wa[4] = {wv.x, wv.y, wv.z, wv.w};
#pragma unroll
            for (int i = 0; i < 4; i++)
#pragma unroll
                for (int j = 0; j < 4; j++)
                    acc[i][j] = fmaf(xa[i], wa[j], acc[i][j]);
        }
    }

#pragma unroll
    for (int i = 0; i < 4; i++) {
        int gr = rowBase + 4 * rg + i;
        if (gr < n) {
            float4 o = make_float4(acc[i][0], acc[i][1], acc[i][2], acc[i][3]);
            reinterpret_cast<float4*>(H)[(size_t)gr * 16 + cg] = o;
        }
    }
}

// --- 6/8. aggregate: out[c] = relu(sum_{e->c} nrm*h[src] + dinv^2*h[c] + b) --
// one wave per node, lane = channel. x8 unroll -> 8 gathers in flight.
__global__ __launch_bounds__(256) void k_aggregate(
    const float* __restrict__ h, const int* __restrict__ offs,
    const int* __restrict__ cnt, const int2* __restrict__ csr,
    const float* __restrict__ dinv, const float* __restrict__ bias,
    float* __restrict__ out, int n) {
    int lane = threadIdx.x & 63;
    int node = blockIdx.x * 4 + (threadIdx.x >> 6);
    if (node >= n) return;
    float di = dinv[node];
    float a0 = h[(size_t)node * 64 + lane] * (di * di);  // self loop
    float a1 = 0.f, a2 = 0.f, a3 = 0.f, a4 = 0.f, a5 = 0.f, a6 = 0.f, a7 = 0.f;
    int s = offs[node];
    int e = s + cnt[node];
    int j = s;
    int e8 = s + ((e - s) & ~7);
    for (; j < e8; j += 8) {
        int2 c0 = csr[j + 0], c1 = csr[j + 1], c2 = csr[j + 2], c3 = csr[j + 3];
        int2 c4 = csr[j + 4], c5 = csr[j + 5], c6 = csr[j + 6], c7 = csr[j + 7];
        float v0 = h[(size_t)c0.x * 64 + lane];
        float v1 = h[(size_t)c1.x * 64 + lane];
        float v2 = h[(size_t)c2.x * 64 + lane];
        float v3 = h[(size_t)c3.x * 64 + lane];
        float v4 = h[(size_t)c4.x * 64 + lane];
        float v5 = h[(size_t)c5.x * 64 + lane];
        float v6 = h[(size_t)c6.x * 64 + lane];
        float v7 = h[(size_t)c7.x * 64 + lane];
        a0 = fmaf(v0, __int_as_float(c0.y), a0);
        a1 = fmaf(v1, __int_as_float(c1.y), a1);
        a2 = fmaf(v2, __int_as_float(c2.y), a2);
        a3 = fmaf(v3, __int_as_float(c3.y), a3);
        a4 = fmaf(v4, __int_as_float(c4.y), a4);
        a5 = fmaf(v5, __int_as_float(c5.y), a5);
        a6 = fmaf(v6, __int_as_float(c6.y), a6);
        a7 = fmaf(v7, __int_as_float(c7.y), a7);
    }
    for (; j < e; ++j) {
        int2 c = csr[j];
        a0 = fmaf(h[(size_t)c.x * 64 + lane], __int_as_float(c.y), a0);
    }
    float r = (((a0 + a1) + (a2 + a3)) + ((a4 + a5) + (a6 + a7))) + bias[lane];
    out[(size_t)node * 64 + lane] = fmaxf(r, 0.0f);
}

// --- 9. mean pool per graph + fused MLP head --------------------------------
__global__ __launch_bounds__(1024) void k_pool_head(
    const float* __restrict__ h, const int* __restrict__ batch, int n,
    const float* __restrict__ Wc1, const float* __restrict__ bc1,
    const float* __restrict__ Wc2, const float* __restrict__ bc2,
    float* __restrict__ out) {
    const int g = blockIdx.x;
    const int t = threadIdx.x;
    const int lane = t & 63, w = t >> 6;   // 16 waves
    __shared__ float sums[16][64];
    __shared__ float pooled[64];
    __shared__ float z[32];

    int start = lower_bound_i(batch, n, g);
    int end   = lower_bound_i(batch, n, g + 1);

    float acc = 0.f;
    for (int i = start + w; i < end; i += 16)
        acc += h[(size_t)i * 64 + lane];
    sums[w][lane] = acc;
    __syncthreads();
    if (w == 0) {
        float v = 0.f;
#pragma unroll
        for (int k = 0; k < 16; k++) v += sums[k][lane];
        float c = (float)(end - start);
        pooled[lane] = v / fmaxf(c, 1.0f);
    }
    __syncthreads();
    if (t < 32) {
        float a = bc1[t];
        for (int k = 0; k < 64; k++) a = fmaf(pooled[k], Wc1[k * 32 + t], a);
        z[t] = fmaxf(a, 0.f);
    }
    __syncthreads();
    if (t < 10) {
        float a = bc2[t];
        for (int k = 0; k < 32; k++) a = fmaf(z[k], Wc2[k * 10 + t], a);
        out[g * 10 + t] = a;
    }
}

// ---------------------------------------------------------------------------
extern "C" void kernel_launch(void* const* d_in, const int* in_sizes, int n_in,
                              void* d_out, int out_size, void* d_ws, size_t ws_size,
                              hipStream_t stream) {
    const float* x    = (const float*)d_in[0];
    const int*   ei   = (const int*)d_in[1];
    const float* ew   = (const float*)d_in[2];
    const int*   bat  = (const int*)d_in[3];
    const float* W1   = (const float*)d_in[4];
    const float* b1   = (const float*)d_in[5];
    const float* W2   = (const float*)d_in[6];
    const float* b2   = (const float*)d_in[7];
    const float* Wc1  = (const float*)d_in[8];
    const float* bc1  = (const float*)d_in[9];
    const float* Wc2  = (const float*)d_in[10];
    const float* bc2  = (const float*)d_in[11];
    float* out = (float*)d_out;

    const int N = in_sizes[0] / 128;
    const int E = in_sizes[2];
    const int G = out_size / 10;

    const int* row = ei;
    const int* col = ei + E;

    // workspace carve-up (256B aligned slices)
    char* p = (char*)d_ws;
    auto alloc = [&](size_t bytes) -> void* {
        void* r = (void*)p;
        p += (bytes + 255) & ~(size_t)255;
        return r;
    };
    float* deg    = (float*)alloc((size_t)N * 4);
    float* dinv   = (float*)alloc((size_t)N * 4);
    int*   cnt    = (int*)  alloc((size_t)N * 4);
    int*   offs   = (int*)  alloc((size_t)N * 4);
    int*   cursor = (int*)  alloc((size_t)N * 4);
    int*   bsums  = (int*)  alloc(8192);
    int2*  csr    = (int2*) alloc((size_t)E * 8);
    float* h      = (float*)alloc((size_t)N * 64 * 4);
    float* o      = (float*)alloc((size_t)N * 64 * 4);

    const int gb_n = (N + TPB - 1) / TPB;
    const int gb_e = (E + TPB - 1) / TPB;
    const int NB   = (N + 1023) / 1024;

    k_init<<<gb_n, TPB, 0, stream>>>(deg, cnt, N);
    k_edge_deg<<<gb_e, TPB, 0, stream>>>(col, ew, deg, cnt, E);
    k_dinv<<<gb_n, TPB, 0, stream>>>(deg, dinv, N);
    k_scan_partial<<<NB, TPB, 0, stream>>>(cnt, bsums, N);
    k_scan_bsums<<<1, 64, 0, stream>>>(bsums, NB);
    k_scan_final<<<NB, TPB, 0, stream>>>(cnt, bsums, offs, cursor, N);
    k_scatter<<<gb_e, TPB, 0, stream>>>(row, col, ew, dinv, cursor, csr, E);

    const int gb_mm = (N + 63) / 64;
    const int gb_ag = (N + 3) / 4;

    // layer 1
    k_matmul<128><<<gb_mm, 256, 0, stream>>>(x, W1, h, N);
    k_aggregate<<<gb_ag, 256, 0, stream>>>(h, offs, cnt, csr, dinv, b1, o, N);
    // layer 2
    k_matmul<64><<<gb_mm, 256, 0, stream>>>(o, W2, h, N);
    k_aggregate<<<gb_ag, 256, 0, stream>>>(h, offs, cnt, csr, dinv, b2, o, N);
    // pool + head
    k_pool_head<<<G, 1024, 0, stream>>>(o, bat, N, Wc1, bc1, Wc2, bc2, out);
}

// Round 3
// 344.088 us; speedup vs baseline: 1.8592x; 1.3460x over previous
//
#include <hip/hip_runtime.h>

// ---------------------------------------------------------------------------
// SimpleGCN: 2x GCNConv (self-loops, symmetric norm) + mean pool + MLP head
// N=100000 nodes, E=1.6M edges, IN=128, HID=64, G=128 graphs, NCLS=10
//
// Round 2 change: k_edge_deg was atomic-bound (146us, WRITE_SIZE = E*64B ->
// every device atomic writes a line through to HBM). Replace 3 atomic ops
// per edge (deg float + cnt int + cursor int) with ONE packed 64-bit atomic:
//   hi24 = in-degree count, lo40 = sum(ew) in 2^-24 fixed point.
// The returned old value's hi bits give each edge a free unique slot index,
// so CSR placement needs no cursor atomic at all.
// ---------------------------------------------------------------------------

#define TPB 256
#define FIX_SHIFT 40
#define FIX_SCALE 16777216.0f   // 2^24

__device__ __forceinline__ int lower_bound_i(const int* __restrict__ a, int n, int key) {
    int lo = 0, hi = n;
    while (lo < hi) {
        int mid = (lo + hi) >> 1;
        if (a[mid] < key) lo = mid + 1; else hi = mid;
    }
    return lo;
}

// --- 1. init packed accumulator ---------------------------------------------
__global__ void k_init(unsigned long long* __restrict__ packed, int n) {
    int i = blockIdx.x * TPB + threadIdx.x;
    if (i < n) packed[i] = 0ULL;
}

// --- 2. one packed atomic per edge; old>>40 = slot within destination -------
__global__ void k_count_slot(const int* __restrict__ col, const float* __restrict__ ew,
                             unsigned long long* __restrict__ packed,
                             int* __restrict__ slot, int E) {
    int e = blockIdx.x * TPB + threadIdx.x;
    if (e < E) {
        int c = col[e];
        unsigned long long add = (1ULL << FIX_SHIFT) |
            (unsigned long long)(ew[e] * FIX_SCALE + 0.5f);
        unsigned long long old = atomicAdd(&packed[c], add);
        slot[e] = (int)(old >> FIX_SHIFT);
    }
}

// --- 3. unpack deg -> dinv, cnt ---------------------------------------------
__global__ void k_dinv(const unsigned long long* __restrict__ packed,
                       float* __restrict__ dinv, int* __restrict__ cnt, int n) {
    int i = blockIdx.x * TPB + threadIdx.x;
    if (i < n) {
        unsigned long long v = packed[i];
        float deg = 1.0f + (float)((double)(v & ((1ULL << FIX_SHIFT) - 1)) *
                                   (1.0 / 16777216.0));
        dinv[i] = 1.0f / sqrtf(deg);      // deg >= 1 (self loop)
        cnt[i] = (int)(v >> FIX_SHIFT);
    }
}

// --- 4. scan (1024 elems per block) -----------------------------------------
__global__ void k_scan_partial(const int* __restrict__ cnt, int* __restrict__ bsums, int n) {
    __shared__ int red[4];
    int b = blockIdx.x, t = threadIdx.x;
    int base = b * 1024;
    int s = 0;
#pragma unroll
    for (int i = 0; i < 4; i++) {
        int idx = base + t + i * TPB;
        if (idx < n) s += cnt[idx];
    }
#pragma unroll
    for (int off = 32; off > 0; off >>= 1) s += __shfl_down(s, off);
    if ((t & 63) == 0) red[t >> 6] = s;
    __syncthreads();
    if (t == 0) bsums[b] = red[0] + red[1] + red[2] + red[3];
}

__global__ void k_scan_bsums(int* __restrict__ bsums, int nb) {
    int l = threadIdx.x;
    int carry = 0;
    for (int base = 0; base < nb; base += 64) {
        int i = base + l;
        int v = (i < nb) ? bsums[i] : 0;
        int orig = v;
#pragma unroll
        for (int off = 1; off < 64; off <<= 1) {
            int x = __shfl_up(v, off);
            if (l >= off) v += x;
        }
        if (i < nb) bsums[i] = v - orig + carry;  // exclusive + carry
        carry += __shfl(v, 63);
    }
}

__global__ void k_scan_final(const int* __restrict__ cnt, const int* __restrict__ boffs,
                             int* __restrict__ offs, int n) {
    __shared__ int ts[TPB];
    int b = blockIdx.x, t = threadIdx.x;
    int base = b * 1024 + 4 * t;
    int v[4]; int s = 0;
#pragma unroll
    for (int i = 0; i < 4; i++) {
        int idx = base + i;
        v[i] = (idx < n) ? cnt[idx] : 0;
        s += v[i];
    }
    ts[t] = s; __syncthreads();
    for (int off = 1; off < TPB; off <<= 1) {
        int x = (t >= off) ? ts[t - off] : 0;
        __syncthreads();
        ts[t] += x;
        __syncthreads();
    }
    int run = ts[t] - s + boffs[b];
#pragma unroll
    for (int i = 0; i < 4; i++) {
        int idx = base + i;
        if (idx < n) offs[idx] = run;
        run += v[i];
    }
}

// --- 5. place edges into CSR: NO atomics ------------------------------------
__global__ void k_place(const int* __restrict__ row, const int* __restrict__ col,
                        const float* __restrict__ ew, const int* __restrict__ slot,
                        const int* __restrict__ offs, const float* __restrict__ dinv,
                        int2* __restrict__ csr, int E) {
    int e = blockIdx.x * TPB + threadIdx.x;
    if (e < E) {
        int r = row[e], c = col[e];
        float nrm = dinv[r] * ew[e] * dinv[c];
        csr[offs[c] + slot[e]] = make_int2(r, __float_as_int(nrm));
    }
}

// --- 6/8. matmul: H[n,64] = X[n,K] @ W[K,64] --------------------------------
template <int K>
__global__ __launch_bounds__(256) void k_matmul(const float* __restrict__ X,
                                                const float* __restrict__ W,
                                                float* __restrict__ H, int n) {
    constexpr int KS = 64;                    // k per stage
    __shared__ __align__(16) float Xs[KS * 68];   // [k][swizzled row quad]
    __shared__ __align__(16) float Ws[K * 64];    // [k][col]
    const int t = threadIdx.x;
    const int rowBase = blockIdx.x * 64;

#pragma unroll
    for (int i = t; i < K * 16; i += 256)
        reinterpret_cast<float4*>(Ws)[i] = reinterpret_cast<const float4*>(W)[i];

    const int cg = t & 15;
    const int rg = t >> 4;
    float acc[4][4] = {{0.f}};

    for (int k0 = 0; k0 < K; k0 += KS) {
        __syncthreads();
        for (int i = t; i < 64 * (KS / 4); i += 256) {
            int r = i / (KS / 4);
            int q = i - r * (KS / 4);
            int gr = rowBase + r;
            float4 v = make_float4(0.f, 0.f, 0.f, 0.f);
            if (gr < n) v = reinterpret_cast<const float4*>(X)[(size_t)gr * (K / 4) + (k0 / 4) + q];
            int g2 = (((r >> 2) ^ (q & 15)) << 2) + (r & 3);
            int kk = q * 4;
            Xs[(kk + 0) * 68 + g2] = v.x;
            Xs[(kk + 1) * 68 + g2] = v.y;
            Xs[(kk + 2) * 68 + g2] = v.z;
            Xs[(kk + 3) * 68 + g2] = v.w;
        }
        __syncthreads();
#pragma unroll 4
        for (int kk = 0; kk < KS; kk++) {
            const float4 xv = *reinterpret_cast<const float4*>(
                &Xs[kk * 68 + ((rg ^ ((kk >> 2) & 15)) << 2)]);
            const float4 wv = *reinterpret_cast<const float4*>(
                &Ws[(k0 + kk) * 64 + 4 * cg]);
            const float xa[4] = {xv.x, xv.y, xv.z, xv.w};
            const float wa[4] = {wv.x, wv.y, wv.z, wv.w};
#pragma unroll
            for (int i = 0; i < 4; i++)
#pragma unroll
                for (int j = 0; j < 4; j++)
                    acc[i][j] = fmaf(xa[i], wa[j], acc[i][j]);
        }
    }

#pragma unroll
    for (int i = 0; i < 4; i++) {
        int gr = rowBase + 4 * rg + i;
        if (gr < n) {
            float4 o = make_float4(acc[i][0], acc[i][1], acc[i][2], acc[i][3]);
            reinterpret_cast<float4*>(H)[(size_t)gr * 16 + cg] = o;
        }
    }
}

// --- 7/9. aggregate: out[c] = relu(sum_{e->c} nrm*h[src] + dinv^2*h[c] + b) --
__global__ __launch_bounds__(256) void k_aggregate(
    const float* __restrict__ h, const int* __restrict__ offs,
    const int* __restrict__ cnt, const int2* __restrict__ csr,
    const float* __restrict__ dinv, const float* __restrict__ bias,
    float* __restrict__ out, int n) {
    int lane = threadIdx.x & 63;
    int node = blockIdx.x * 4 + (threadIdx.x >> 6);
    if (node >= n) return;
    float di = dinv[node];
    float a0 = h[(size_t)node * 64 + lane] * (di * di);  // self loop
    float a1 = 0.f, a2 = 0.f, a3 = 0.f, a4 = 0.f, a5 = 0.f, a6 = 0.f, a7 = 0.f;
    int s = offs[node];
    int e = s + cnt[node];
    int j = s;
    int e8 = s + ((e - s) & ~7);
    for (; j < e8; j += 8) {
        int2 c0 = csr[j + 0], c1 = csr[j + 1], c2 = csr[j + 2], c3 = csr[j + 3];
        int2 c4 = csr[j + 4], c5 = csr[j + 5], c6 = csr[j + 6], c7 = csr[j + 7];
        float v0 = h[(size_t)c0.x * 64 + lane];
        float v1 = h[(size_t)c1.x * 64 + lane];
        float v2 = h[(size_t)c2.x * 64 + lane];
        float v3 = h[(size_t)c3.x * 64 + lane];
        float v4 = h[(size_t)c4.x * 64 + lane];
        float v5 = h[(size_t)c5.x * 64 + lane];
        float v6 = h[(size_t)c6.x * 64 + lane];
        float v7 = h[(size_t)c7.x * 64 + lane];
        a0 = fmaf(v0, __int_as_float(c0.y), a0);
        a1 = fmaf(v1, __int_as_float(c1.y), a1);
        a2 = fmaf(v2, __int_as_float(c2.y), a2);
        a3 = fmaf(v3, __int_as_float(c3.y), a3);
        a4 = fmaf(v4, __int_as_float(c4.y), a4);
        a5 = fmaf(v5, __int_as_float(c5.y), a5);
        a6 = fmaf(v6, __int_as_float(c6.y), a6);
        a7 = fmaf(v7, __int_as_float(c7.y), a7);
    }
    for (; j < e; ++j) {
        int2 c = csr[j];
        a0 = fmaf(h[(size_t)c.x * 64 + lane], __int_as_float(c.y), a0);
    }
    float r = (((a0 + a1) + (a2 + a3)) + ((a4 + a5) + (a6 + a7))) + bias[lane];
    out[(size_t)node * 64 + lane] = fmaxf(r, 0.0f);
}

// --- 10. mean pool per graph + fused MLP head -------------------------------
__global__ __launch_bounds__(1024) void k_pool_head(
    const float* __restrict__ h, const int* __restrict__ batch, int n,
    const float* __restrict__ Wc1, const float* __restrict__ bc1,
    const float* __restrict__ Wc2, const float* __restrict__ bc2,
    float* __restrict__ out) {
    const int g = blockIdx.x;
    const int t = threadIdx.x;
    const int lane = t & 63, w = t >> 6;   // 16 waves
    __shared__ float sums[16][64];
    __shared__ float pooled[64];
    __shared__ float z[32];

    int start = lower_bound_i(batch, n, g);
    int end   = lower_bound_i(batch, n, g + 1);

    float acc = 0.f;
    for (int i = start + w; i < end; i += 16)
        acc += h[(size_t)i * 64 + lane];
    sums[w][lane] = acc;
    __syncthreads();
    if (w == 0) {
        float v = 0.f;
#pragma unroll
        for (int k = 0; k < 16; k++) v += sums[k][lane];
        float c = (float)(end - start);
        pooled[lane] = v / fmaxf(c, 1.0f);
    }
    __syncthreads();
    if (t < 32) {
        float a = bc1[t];
        for (int k = 0; k < 64; k++) a = fmaf(pooled[k], Wc1[k * 32 + t], a);
        z[t] = fmaxf(a, 0.f);
    }
    __syncthreads();
    if (t < 10) {
        float a = bc2[t];
        for (int k = 0; k < 32; k++) a = fmaf(z[k], Wc2[k * 10 + t], a);
        out[g * 10 + t] = a;
    }
}

// ---------------------------------------------------------------------------
extern "C" void kernel_launch(void* const* d_in, const int* in_sizes, int n_in,
                              void* d_out, int out_size, void* d_ws, size_t ws_size,
                              hipStream_t stream) {
    const float* x    = (const float*)d_in[0];
    const int*   ei   = (const int*)d_in[1];
    const float* ew   = (const float*)d_in[2];
    const int*   bat  = (const int*)d_in[3];
    const float* W1   = (const float*)d_in[4];
    const float* b1   = (const float*)d_in[5];
    const float* W2   = (const float*)d_in[6];
    const float* b2   = (const float*)d_in[7];
    const float* Wc1  = (const float*)d_in[8];
    const float* bc1  = (const float*)d_in[9];
    const float* Wc2  = (const float*)d_in[10];
    const float* bc2  = (const float*)d_in[11];
    float* out = (float*)d_out;

    const int N = in_sizes[0] / 128;
    const int E = in_sizes[2];
    const int G = out_size / 10;

    const int* row = ei;
    const int* col = ei + E;

    // workspace carve-up (256B aligned slices)
    char* p = (char*)d_ws;
    auto alloc = [&](size_t bytes) -> void* {
        void* r = (void*)p;
        p += (bytes + 255) & ~(size_t)255;
        return r;
    };
    unsigned long long* packed = (unsigned long long*)alloc((size_t)N * 8);
    float* dinv   = (float*)alloc((size_t)N * 4);
    int*   cnt    = (int*)  alloc((size_t)N * 4);
    int*   offs   = (int*)  alloc((size_t)N * 4);
    int*   slot   = (int*)  alloc((size_t)E * 4);
    int*   bsums  = (int*)  alloc(8192);
    int2*  csr    = (int2*) alloc((size_t)E * 8);
    float* h      = (float*)alloc((size_t)N * 64 * 4);
    float* o      = (float*)alloc((size_t)N * 64 * 4);

    const int gb_n = (N + TPB - 1) / TPB;
    const int gb_e = (E + TPB - 1) / TPB;
    const int NB   = (N + 1023) / 1024;

    k_init<<<gb_n, TPB, 0, stream>>>(packed, N);
    k_count_slot<<<gb_e, TPB, 0, stream>>>(col, ew, packed, slot, E);
    k_dinv<<<gb_n, TPB, 0, stream>>>(packed, dinv, cnt, N);
    k_scan_partial<<<NB, TPB, 0, stream>>>(cnt, bsums, N);
    k_scan_bsums<<<1, 64, 0, stream>>>(bsums, NB);
    k_scan_final<<<NB, TPB, 0, stream>>>(cnt, bsums, offs, N);
    k_place<<<gb_e, TPB, 0, stream>>>(row, col, ew, slot, offs, dinv, csr, E);

    const int gb_mm = (N + 63) / 64;
    const int gb_ag = (N + 3) / 4;

    // layer 1
    k_matmul<128><<<gb_mm, 256, 0, stream>>>(x, W1, h, N);
    k_aggregate<<<gb_ag, 256, 0, stream>>>(h, offs, cnt, csr, dinv, b1, o, N);
    // layer 2
    k_matmul<64><<<gb_mm, 256, 0, stream>>>(o, W2, h, N);
    k_aggregate<<<gb_ag, 256, 0, stream>>>(h, offs, cnt, csr, dinv, b2, o, N);
    // pool + head
    k_pool_head<<<G, 1024, 0, stream>>>(o, bat, N, Wc1, bc1, Wc2, bc2, out);
}

// Round 4
// 307.144 us; speedup vs baseline: 2.0828x; 1.1203x over previous
//
#include <hip/hip_runtime.h>

// ---------------------------------------------------------------------------
// SimpleGCN: 2x GCNConv (self-loops, symmetric norm) + mean pool + MLP head
// N=100000 nodes, E=1.6M edges, IN=128, HID=64, G=128 graphs, NCLS=10
//
// Round 3 changes:
//  - aggregate: register-stage each node's CSR (<=64 entries, one coalesced
//    512B load), broadcast src/ew per edge via readlane -> scalar regs; 8
//    independent gathers in flight with no CSR load in the dependency chain.
//  - prescale h' = dinv (.) (X@W) in the matmul epilogue; aggregate computes
//    relu(dinv[c]*(sum ew*h'[src] + h'[c]) + b)  == identical math.
//  - CSR stores (row, ew) -> k_place no longer does random dinv gathers.
// ---------------------------------------------------------------------------

#define TPB 256
#define FIX_SHIFT 40
#define FIX_SCALE 16777216.0f   // 2^24

__device__ __forceinline__ int lower_bound_i(const int* __restrict__ a, int n, int key) {
    int lo = 0, hi = n;
    while (lo < hi) {
        int mid = (lo + hi) >> 1;
        if (a[mid] < key) lo = mid + 1; else hi = mid;
    }
    return lo;
}

// --- 1. init packed accumulator ---------------------------------------------
__global__ void k_init(unsigned long long* __restrict__ packed, int n) {
    int i = blockIdx.x * TPB + threadIdx.x;
    if (i < n) packed[i] = 0ULL;
}

// --- 2. one packed atomic per edge; old>>40 = slot within destination -------
__global__ void k_count_slot(const int* __restrict__ col, const float* __restrict__ ew,
                             unsigned long long* __restrict__ packed,
                             int* __restrict__ slot, int E) {
    int e = blockIdx.x * TPB + threadIdx.x;
    if (e < E) {
        int c = col[e];
        unsigned long long add = (1ULL << FIX_SHIFT) |
            (unsigned long long)(ew[e] * FIX_SCALE + 0.5f);
        unsigned long long old = atomicAdd(&packed[c], add);
        slot[e] = (int)(old >> FIX_SHIFT);
    }
}

// --- 3. unpack deg -> dinv, cnt ---------------------------------------------
__global__ void k_dinv(const unsigned long long* __restrict__ packed,
                       float* __restrict__ dinv, int* __restrict__ cnt, int n) {
    int i = blockIdx.x * TPB + threadIdx.x;
    if (i < n) {
        unsigned long long v = packed[i];
        float deg = 1.0f + (float)((double)(v & ((1ULL << FIX_SHIFT) - 1)) *
                                   (1.0 / 16777216.0));
        dinv[i] = 1.0f / sqrtf(deg);      // deg >= 1 (self loop)
        cnt[i] = (int)(v >> FIX_SHIFT);
    }
}

// --- 4. scan (1024 elems per block) -----------------------------------------
__global__ void k_scan_partial(const int* __restrict__ cnt, int* __restrict__ bsums, int n) {
    __shared__ int red[4];
    int b = blockIdx.x, t = threadIdx.x;
    int base = b * 1024;
    int s = 0;
#pragma unroll
    for (int i = 0; i < 4; i++) {
        int idx = base + t + i * TPB;
        if (idx < n) s += cnt[idx];
    }
#pragma unroll
    for (int off = 32; off > 0; off >>= 1) s += __shfl_down(s, off);
    if ((t & 63) == 0) red[t >> 6] = s;
    __syncthreads();
    if (t == 0) bsums[b] = red[0] + red[1] + red[2] + red[3];
}

__global__ void k_scan_bsums(int* __restrict__ bsums, int nb) {
    int l = threadIdx.x;
    int carry = 0;
    for (int base = 0; base < nb; base += 64) {
        int i = base + l;
        int v = (i < nb) ? bsums[i] : 0;
        int orig = v;
#pragma unroll
        for (int off = 1; off < 64; off <<= 1) {
            int x = __shfl_up(v, off);
            if (l >= off) v += x;
        }
        if (i < nb) bsums[i] = v - orig + carry;  // exclusive + carry
        carry += __shfl(v, 63);
    }
}

__global__ void k_scan_final(const int* __restrict__ cnt, const int* __restrict__ boffs,
                             int* __restrict__ offs, int n) {
    __shared__ int ts[TPB];
    int b = blockIdx.x, t = threadIdx.x;
    int base = b * 1024 + 4 * t;
    int v[4]; int s = 0;
#pragma unroll
    for (int i = 0; i < 4; i++) {
        int idx = base + i;
        v[i] = (idx < n) ? cnt[idx] : 0;
        s += v[i];
    }
    ts[t] = s; __syncthreads();
    for (int off = 1; off < TPB; off <<= 1) {
        int x = (t >= off) ? ts[t - off] : 0;
        __syncthreads();
        ts[t] += x;
        __syncthreads();
    }
    int run = ts[t] - s + boffs[b];
#pragma unroll
    for (int i = 0; i < 4; i++) {
        int idx = base + i;
        if (idx < n) offs[idx] = run;
        run += v[i];
    }
}

// --- 5. place edges into CSR: (row, ew), no atomics, no random reads --------
__global__ void k_place(const int* __restrict__ row, const int* __restrict__ col,
                        const float* __restrict__ ew, const int* __restrict__ slot,
                        const int* __restrict__ offs,
                        int2* __restrict__ csr, int E) {
    int e = blockIdx.x * TPB + threadIdx.x;
    if (e < E) {
        int c = col[e];
        csr[offs[c] + slot[e]] = make_int2(row[e], __float_as_int(ew[e]));
    }
}

// --- 6/8. matmul: H'[n,64] = dinv (.) (X[n,K] @ W[K,64]) --------------------
template <int K>
__global__ __launch_bounds__(256) void k_matmul(const float* __restrict__ X,
                                                const float* __restrict__ W,
                                                const float* __restrict__ dinv,
                                                float* __restrict__ H, int n) {
    constexpr int KS = 64;                    // k per stage
    __shared__ __align__(16) float Xs[KS * 68];   // [k][swizzled row quad]
    __shared__ __align__(16) float Ws[K * 64];    // [k][col]
    const int t = threadIdx.x;
    const int rowBase = blockIdx.x * 64;

#pragma unroll
    for (int i = t; i < K * 16; i += 256)
        reinterpret_cast<float4*>(Ws)[i] = reinterpret_cast<const float4*>(W)[i];

    const int cg = t & 15;
    const int rg = t >> 4;
    float acc[4][4] = {{0.f}};

    for (int k0 = 0; k0 < K; k0 += KS) {
        __syncthreads();
        for (int i = t; i < 64 * (KS / 4); i += 256) {
            int r = i / (KS / 4);
            int q = i - r * (KS / 4);
            int gr = rowBase + r;
            float4 v = make_float4(0.f, 0.f, 0.f, 0.f);
            if (gr < n) v = reinterpret_cast<const float4*>(X)[(size_t)gr * (K / 4) + (k0 / 4) + q];
            int g2 = (((r >> 2) ^ (q & 15)) << 2) + (r & 3);
            int kk = q * 4;
            Xs[(kk + 0) * 68 + g2] = v.x;
            Xs[(kk + 1) * 68 + g2] = v.y;
            Xs[(kk + 2) * 68 + g2] = v.z;
            Xs[(kk + 3) * 68 + g2] = v.w;
        }
        __syncthreads();
#pragma unroll 4
        for (int kk = 0; kk < KS; kk++) {
            const float4 xv = *reinterpret_cast<const float4*>(
                &Xs[kk * 68 + ((rg ^ ((kk >> 2) & 15)) << 2)]);
            const float4 wv = *reinterpret_cast<const float4*>(
                &Ws[(k0 + kk) * 64 + 4 * cg]);
            const float xa[4] = {xv.x, xv.y, xv.z, xv.w};
            const float wa[4] = {wv.x, wv.y, wv.z, wv.w};
#pragma unroll
            for (int i = 0; i < 4; i++)
#pragma unroll
                for (int j = 0; j < 4; j++)
                    acc[i][j] = fmaf(xa[i], wa[j], acc[i][j]);
        }
    }

#pragma unroll
    for (int i = 0; i < 4; i++) {
        int gr = rowBase + 4 * rg + i;
        if (gr < n) {
            float dv = dinv[gr];
            float4 o = make_float4(acc[i][0] * dv, acc[i][1] * dv,
                                   acc[i][2] * dv, acc[i][3] * dv);
            reinterpret_cast<float4*>(H)[(size_t)gr * 16 + cg] = o;
        }
    }
}

// --- 7/9. aggregate: out[c] = relu(dinv[c]*(sum ew*h'[src] + h'[c]) + b) ----
// wave per node, lane = channel. CSR register-staged; readlane broadcasts
// src/ew to scalars -> 8 back-to-back independent gathers per iteration.
__global__ __launch_bounds__(256) void k_aggregate(
    const float* __restrict__ hp, const int* __restrict__ offs,
    const int* __restrict__ cnt, const int2* __restrict__ csr,
    const float* __restrict__ dinv, const float* __restrict__ bias,
    float* __restrict__ out, int n) {
    int lane = threadIdx.x & 63;
    int node = blockIdx.x * 4 + (threadIdx.x >> 6);
    if (node >= n) return;
    int c = cnt[node];
    int s = offs[node];

    // register-stage up to 64 CSR entries; pad = (self, 0.0) -> exact no-op
    int2 mc = make_int2(node, 0);
    if (lane < c) mc = csr[s + lane];
    int cc = min(c, 64);
    int c8 = (cc + 7) & ~7;

    float a0 = hp[(size_t)node * 64 + lane];  // self term h'[c] (coeff 1)
    float a1 = 0.f, a2 = 0.f, a3 = 0.f, a4 = 0.f, a5 = 0.f, a6 = 0.f, a7 = 0.f;

    for (int j = 0; j < c8; j += 8) {
        int s0 = __builtin_amdgcn_readlane(mc.x, j + 0);
        int w0 = __builtin_amdgcn_readlane(mc.y, j + 0);
        int s1 = __builtin_amdgcn_readlane(mc.x, j + 1);
        int w1 = __builtin_amdgcn_readlane(mc.y, j + 1);
        int s2 = __builtin_amdgcn_readlane(mc.x, j + 2);
        int w2 = __builtin_amdgcn_readlane(mc.y, j + 2);
        int s3 = __builtin_amdgcn_readlane(mc.x, j + 3);
        int w3 = __builtin_amdgcn_readlane(mc.y, j + 3);
        int s4 = __builtin_amdgcn_readlane(mc.x, j + 4);
        int w4 = __builtin_amdgcn_readlane(mc.y, j + 4);
        int s5 = __builtin_amdgcn_readlane(mc.x, j + 5);
        int w5 = __builtin_amdgcn_readlane(mc.y, j + 5);
        int s6 = __builtin_amdgcn_readlane(mc.x, j + 6);
        int w6 = __builtin_amdgcn_readlane(mc.y, j + 6);
        int s7 = __builtin_amdgcn_readlane(mc.x, j + 7);
        int w7 = __builtin_amdgcn_readlane(mc.y, j + 7);
        float v0 = hp[(size_t)s0 * 64 + lane];
        float v1 = hp[(size_t)s1 * 64 + lane];
        float v2 = hp[(size_t)s2 * 64 + lane];
        float v3 = hp[(size_t)s3 * 64 + lane];
        float v4 = hp[(size_t)s4 * 64 + lane];
        float v5 = hp[(size_t)s5 * 64 + lane];
        float v6 = hp[(size_t)s6 * 64 + lane];
        float v7 = hp[(size_t)s7 * 64 + lane];
        a0 = fmaf(v0, __int_as_float(w0), a0);
        a1 = fmaf(v1, __int_as_float(w1), a1);
        a2 = fmaf(v2, __int_as_float(w2), a2);
        a3 = fmaf(v3, __int_as_float(w3), a3);
        a4 = fmaf(v4, __int_as_float(w4), a4);
        a5 = fmaf(v5, __int_as_float(w5), a5);
        a6 = fmaf(v6, __int_as_float(w6), a6);
        a7 = fmaf(v7, __int_as_float(w7), a7);
    }
    // rare overflow (deg > 64)
    for (int j = 64; j < c; ++j) {
        int2 e = csr[s + j];
        a0 = fmaf(hp[(size_t)e.x * 64 + lane], __int_as_float(e.y), a0);
    }
    float r = (((a0 + a1) + (a2 + a3)) + ((a4 + a5) + (a6 + a7)));
    float o = fmaf(r, dinv[node], bias[lane]);
    out[(size_t)node * 64 + lane] = fmaxf(o, 0.0f);
}

// --- 10. mean pool per graph + fused MLP head -------------------------------
__global__ __launch_bounds__(1024) void k_pool_head(
    const float* __restrict__ h, const int* __restrict__ batch, int n,
    const float* __restrict__ Wc1, const float* __restrict__ bc1,
    const float* __restrict__ Wc2, const float* __restrict__ bc2,
    float* __restrict__ out) {
    const int g = blockIdx.x;
    const int t = threadIdx.x;
    const int lane = t & 63, w = t >> 6;   // 16 waves
    __shared__ float sums[16][64];
    __shared__ float pooled[64];
    __shared__ float z[32];

    int start = lower_bound_i(batch, n, g);
    int end   = lower_bound_i(batch, n, g + 1);

    float acc = 0.f;
    for (int i = start + w; i < end; i += 16)
        acc += h[(size_t)i * 64 + lane];
    sums[w][lane] = acc;
    __syncthreads();
    if (w == 0) {
        float v = 0.f;
#pragma unroll
        for (int k = 0; k < 16; k++) v += sums[k][lane];
        float c = (float)(end - start);
        pooled[lane] = v / fmaxf(c, 1.0f);
    }
    __syncthreads();
    if (t < 32) {
        float a = bc1[t];
        for (int k = 0; k < 64; k++) a = fmaf(pooled[k], Wc1[k * 32 + t], a);
        z[t] = fmaxf(a, 0.f);
    }
    __syncthreads();
    if (t < 10) {
        float a = bc2[t];
        for (int k = 0; k < 32; k++) a = fmaf(z[k], Wc2[k * 10 + t], a);
        out[g * 10 + t] = a;
    }
}

// ---------------------------------------------------------------------------
extern "C" void kernel_launch(void* const* d_in, const int* in_sizes, int n_in,
                              void* d_out, int out_size, void* d_ws, size_t ws_size,
                              hipStream_t stream) {
    const float* x    = (const float*)d_in[0];
    const int*   ei   = (const int*)d_in[1];
    const float* ew   = (const float*)d_in[2];
    const int*   bat  = (const int*)d_in[3];
    const float* W1   = (const float*)d_in[4];
    const float* b1   = (const float*)d_in[5];
    const float* W2   = (const float*)d_in[6];
    const float* b2   = (const float*)d_in[7];
    const float* Wc1  = (const float*)d_in[8];
    const float* bc1  = (const float*)d_in[9];
    const float* Wc2  = (const float*)d_in[10];
    const float* bc2  = (const float*)d_in[11];
    float* out = (float*)d_out;

    const int N = in_sizes[0] / 128;
    const int E = in_sizes[2];
    const int G = out_size / 10;

    const int* row = ei;
    const int* col = ei + E;

    // workspace carve-up (256B aligned slices)
    char* p = (char*)d_ws;
    auto alloc = [&](size_t bytes) -> void* {
        void* r = (void*)p;
        p += (bytes + 255) & ~(size_t)255;
        return r;
    };
    unsigned long long* packed = (unsigned long long*)alloc((size_t)N * 8);
    float* dinv   = (float*)alloc((size_t)N * 4);
    int*   cnt    = (int*)  alloc((size_t)N * 4);
    int*   offs   = (int*)  alloc((size_t)N * 4);
    int*   slot   = (int*)  alloc((size_t)E * 4);
    int*   bsums  = (int*)  alloc(8192);
    int2*  csr    = (int2*) alloc((size_t)E * 8);
    float* h      = (float*)alloc((size_t)N * 64 * 4);
    float* o      = (float*)alloc((size_t)N * 64 * 4);

    const int gb_n = (N + TPB - 1) / TPB;
    const int gb_e = (E + TPB - 1) / TPB;
    const int NB   = (N + 1023) / 1024;

    k_init<<<gb_n, TPB, 0, stream>>>(packed, N);
    k_count_slot<<<gb_e, TPB, 0, stream>>>(col, ew, packed, slot, E);
    k_dinv<<<gb_n, TPB, 0, stream>>>(packed, dinv, cnt, N);
    k_scan_partial<<<NB, TPB, 0, stream>>>(cnt, bsums, N);
    k_scan_bsums<<<1, 64, 0, stream>>>(bsums, NB);
    k_scan_final<<<NB, TPB, 0, stream>>>(cnt, bsums, offs, N);
    k_place<<<gb_e, TPB, 0, stream>>>(row, col, ew, slot, offs, csr, E);

    const int gb_mm = (N + 63) / 64;
    const int gb_ag = (N + 3) / 4;

    // layer 1
    k_matmul<128><<<gb_mm, 256, 0, stream>>>(x, W1, dinv, h, N);
    k_aggregate<<<gb_ag, 256, 0, stream>>>(h, offs, cnt, csr, dinv, b1, o, N);
    // layer 2
    k_matmul<64><<<gb_mm, 256, 0, stream>>>(o, W2, dinv, h, N);
    k_aggregate<<<gb_ag, 256, 0, stream>>>(h, offs, cnt, csr, dinv, b2, o, N);
    // pool + head
    k_pool_head<<<G, 1024, 0, stream>>>(o, bat, N, Wc1, bc1, Wc2, bc2, out);
}

// Round 5
// 261.875 us; speedup vs baseline: 2.4429x; 1.1729x over previous
//
#include <hip/hip_runtime.h>

// ---------------------------------------------------------------------------
// SimpleGCN: 2x GCNConv (self-loops, symmetric norm) + mean pool + MLP head
// N=100000 nodes, E=1.6M edges, IN=128, HID=64, G=128 graphs, NCLS=10
//
// Round 4 change: the CSR build was global-atomic-bound (k_count_slot 76us,
// atomic write-through wall at ~21G atomics/s). Rebuild CSR with a bucketed
// counting sort: bucket = 256 consecutive nodes (col>>8, K=391 buckets).
//   A) per-block LDS histogram of bucket counts -> bh[(bucket, block)]
//   B) exclusive scan of bh (reused 3-kernel scan)
//   C) partition edges into bucket-contiguous array (LDS cursors only)
//   D) per-bucket block: LDS per-node count + fixed-point sum(ew) (32-bit LDS
//      atomics, same 2^-24 quantization as before), LDS scan -> offs/cnt/dinv,
//      LDS cursors -> final CSR. ZERO global atomics anywhere.
// part arrays alias h (dead before matmul1), so workspace stays ~66MB.
// ---------------------------------------------------------------------------

#define TPB 256
#define FIX_SCALE 16777216.0f   // 2^24
#define BKT_BITS 8              // bucket = 256 nodes
#define PART_BLOCKS 256         // blocks in hist/partition passes

__device__ __forceinline__ int lower_bound_i(const int* __restrict__ a, int n, int key) {
    int lo = 0, hi = n;
    while (lo < hi) {
        int mid = (lo + hi) >> 1;
        if (a[mid] < key) lo = mid + 1; else hi = mid;
    }
    return lo;
}

// --- A. per-block bucket histogram ------------------------------------------
__global__ __launch_bounds__(256) void k_histA(const int* __restrict__ col, int E, int CH,
                                               int K, int* __restrict__ bh) {
    __shared__ int hist[512];
    int b = blockIdx.x, t = threadIdx.x;
    for (int i = t; i < K; i += 256) hist[i] = 0;
    __syncthreads();
    int s = b * CH, e = min(E, s + CH);
    for (int i = s + t; i < e; i += 256) atomicAdd(&hist[col[i] >> BKT_BITS], 1);
    __syncthreads();
    for (int i = t; i < K; i += 256) bh[i * PART_BLOCKS + b] = hist[i];
}

// --- scan (1024 elems per block) ---------------------------------------------
__global__ void k_scan_partial(const int* __restrict__ cnt, int* __restrict__ bsums, int n) {
    __shared__ int red[4];
    int b = blockIdx.x, t = threadIdx.x;
    int base = b * 1024;
    int s = 0;
#pragma unroll
    for (int i = 0; i < 4; i++) {
        int idx = base + t + i * TPB;
        if (idx < n) s += cnt[idx];
    }
#pragma unroll
    for (int off = 32; off > 0; off >>= 1) s += __shfl_down(s, off);
    if ((t & 63) == 0) red[t >> 6] = s;
    __syncthreads();
    if (t == 0) bsums[b] = red[0] + red[1] + red[2] + red[3];
}

__global__ void k_scan_bsums(int* __restrict__ bsums, int nb) {
    int l = threadIdx.x;
    int carry = 0;
    for (int base = 0; base < nb; base += 64) {
        int i = base + l;
        int v = (i < nb) ? bsums[i] : 0;
        int orig = v;
#pragma unroll
        for (int off = 1; off < 64; off <<= 1) {
            int x = __shfl_up(v, off);
            if (l >= off) v += x;
        }
        if (i < nb) bsums[i] = v - orig + carry;  // exclusive + carry
        carry += __shfl(v, 63);
    }
}

__global__ void k_scan_final(const int* __restrict__ cnt, const int* __restrict__ boffs,
                             int* __restrict__ offs, int n) {
    __shared__ int ts[TPB];
    int b = blockIdx.x, t = threadIdx.x;
    int base = b * 1024 + 4 * t;
    int v[4]; int s = 0;
#pragma unroll
    for (int i = 0; i < 4; i++) {
        int idx = base + i;
        v[i] = (idx < n) ? cnt[idx] : 0;
        s += v[i];
    }
    ts[t] = s; __syncthreads();
    for (int off = 1; off < TPB; off <<= 1) {
        int x = (t >= off) ? ts[t - off] : 0;
        __syncthreads();
        ts[t] += x;
        __syncthreads();
    }
    int run = ts[t] - s + boffs[b];
#pragma unroll
    for (int i = 0; i < 4; i++) {
        int idx = base + i;
        if (idx < n) offs[idx] = run;
        run += v[i];
    }
}

// --- C. partition edges by bucket (LDS cursors, no global atomics) ----------
__global__ __launch_bounds__(256) void k_partB(const int* __restrict__ row,
                                               const int* __restrict__ col,
                                               const float* __restrict__ ew,
                                               const int* __restrict__ bhs,
                                               int E, int CH, int K,
                                               int2* __restrict__ part2,
                                               int* __restrict__ partc) {
    __shared__ int cur[512];
    int b = blockIdx.x, t = threadIdx.x;
    for (int i = t; i < K; i += 256) cur[i] = bhs[i * PART_BLOCKS + b];
    __syncthreads();
    int s = b * CH, e = min(E, s + CH);
    for (int i = s + t; i < e; i += 256) {
        int c = col[i];
        int pos = atomicAdd(&cur[c >> BKT_BITS], 1);
        part2[pos] = make_int2(row[i], __float_as_int(ew[i]));
        partc[pos] = c;
    }
}

// --- D. per-bucket CSR finalize ----------------------------------------------
__global__ __launch_bounds__(256) void k_csrC(const int2* __restrict__ part2,
                                              const int* __restrict__ partc,
                                              const int* __restrict__ bhs,
                                              int K, int N, int E,
                                              int* __restrict__ offs, int* __restrict__ cnt,
                                              float* __restrict__ dinv,
                                              int2* __restrict__ csr) {
    __shared__ int lcnt[256];
    __shared__ unsigned lew[256];
    __shared__ int lcur[256];
    __shared__ int ts[256];
    int k = blockIdx.x, t = threadIdx.x;
    int n0 = k << BKT_BITS;
    lcnt[t] = 0; lew[t] = 0;
    __syncthreads();
    int estart = bhs[k * PART_BLOCKS];
    int eend   = (k + 1 < K) ? bhs[(k + 1) * PART_BLOCKS] : E;
    for (int i = estart + t; i < eend; i += 256) {
        int c = partc[i] - n0;
        atomicAdd(&lcnt[c], 1);
        float w = __int_as_float(part2[i].y);
        atomicAdd(&lew[c], (unsigned)(w * FIX_SCALE + 0.5f));
    }
    __syncthreads();
    int myc = lcnt[t];
    ts[t] = myc; __syncthreads();
    for (int off = 1; off < 256; off <<= 1) {
        int x = (t >= off) ? ts[t - off] : 0;
        __syncthreads();
        ts[t] += x;
        __syncthreads();
    }
    int goff = estart + ts[t] - myc;   // global CSR offset for node n0+t
    int node = n0 + t;
    if (node < N) {
        offs[node] = goff;
        cnt[node]  = myc;
        float deg = 1.0f + (float)((double)lew[t] * (1.0 / 16777216.0));
        dinv[node] = 1.0f / sqrtf(deg);
    }
    lcur[t] = goff;
    __syncthreads();
    for (int i = estart + t; i < eend; i += 256) {
        int c = partc[i] - n0;
        int pos = atomicAdd(&lcur[c], 1);
        csr[pos] = part2[i];
    }
}

// --- matmul: H'[n,64] = dinv (.) (X[n,K] @ W[K,64]) -------------------------
template <int K>
__global__ __launch_bounds__(256) void k_matmul(const float* __restrict__ X,
                                                const float* __restrict__ W,
                                                const float* __restrict__ dinv,
                                                float* __restrict__ H, int n) {
    constexpr int KS = 64;                    // k per stage
    __shared__ __align__(16) float Xs[KS * 68];   // [k][swizzled row quad]
    __shared__ __align__(16) float Ws[K * 64];    // [k][col]
    const int t = threadIdx.x;
    const int rowBase = blockIdx.x * 64;

#pragma unroll
    for (int i = t; i < K * 16; i += 256)
        reinterpret_cast<float4*>(Ws)[i] = reinterpret_cast<const float4*>(W)[i];

    const int cg = t & 15;
    const int rg = t >> 4;
    float acc[4][4] = {{0.f}};

    for (int k0 = 0; k0 < K; k0 += KS) {
        __syncthreads();
        for (int i = t; i < 64 * (KS / 4); i += 256) {
            int r = i / (KS / 4);
            int q = i - r * (KS / 4);
            int gr = rowBase + r;
            float4 v = make_float4(0.f, 0.f, 0.f, 0.f);
            if (gr < n) v = reinterpret_cast<const float4*>(X)[(size_t)gr * (K / 4) + (k0 / 4) + q];
            int g2 = (((r >> 2) ^ (q & 15)) << 2) + (r & 3);
            int kk = q * 4;
            Xs[(kk + 0) * 68 + g2] = v.x;
            Xs[(kk + 1) * 68 + g2] = v.y;
            Xs[(kk + 2) * 68 + g2] = v.z;
            Xs[(kk + 3) * 68 + g2] = v.w;
        }
        __syncthreads();
#pragma unroll 4
        for (int kk = 0; kk < KS; kk++) {
            const float4 xv = *reinterpret_cast<const float4*>(
                &Xs[kk * 68 + ((rg ^ ((kk >> 2) & 15)) << 2)]);
            const float4 wv = *reinterpret_cast<const float4*>(
                &Ws[(k0 + kk) * 64 + 4 * cg]);
            const float xa[4] = {xv.x, xv.y, xv.z, xv.w};
            const float wa[4] = {wv.x, wv.y, wv.z, wv.w};
#pragma unroll
            for (int i = 0; i < 4; i++)
#pragma unroll
                for (int j = 0; j < 4; j++)
                    acc[i][j] = fmaf(xa[i], wa[j], acc[i][j]);
        }
    }

#pragma unroll
    for (int i = 0; i < 4; i++) {
        int gr = rowBase + 4 * rg + i;
        if (gr < n) {
            float dv = dinv[gr];
            float4 o = make_float4(acc[i][0] * dv, acc[i][1] * dv,
                                   acc[i][2] * dv, acc[i][3] * dv);
            reinterpret_cast<float4*>(H)[(size_t)gr * 16 + cg] = o;
        }
    }
}

// --- aggregate: out[c] = relu(dinv[c]*(sum ew*h'[src] + h'[c]) + b) ---------
__global__ __launch_bounds__(256) void k_aggregate(
    const float* __restrict__ hp, const int* __restrict__ offs,
    const int* __restrict__ cnt, const int2* __restrict__ csr,
    const float* __restrict__ dinv, const float* __restrict__ bias,
    float* __restrict__ out, int n) {
    int lane = threadIdx.x & 63;
    int node = blockIdx.x * 4 + (threadIdx.x >> 6);
    if (node >= n) return;
    int c = cnt[node];
    int s = offs[node];

    // register-stage up to 64 CSR entries; pad = (self, 0.0) -> exact no-op
    int2 mc = make_int2(node, 0);
    if (lane < c) mc = csr[s + lane];
    int cc = min(c, 64);
    int c8 = (cc + 7) & ~7;

    float a0 = hp[(size_t)node * 64 + lane];  // self term h'[c] (coeff 1)
    float a1 = 0.f, a2 = 0.f, a3 = 0.f, a4 = 0.f, a5 = 0.f, a6 = 0.f, a7 = 0.f;

    for (int j = 0; j < c8; j += 8) {
        int s0 = __builtin_amdgcn_readlane(mc.x, j + 0);
        int w0 = __builtin_amdgcn_readlane(mc.y, j + 0);
        int s1 = __builtin_amdgcn_readlane(mc.x, j + 1);
        int w1 = __builtin_amdgcn_readlane(mc.y, j + 1);
        int s2 = __builtin_amdgcn_readlane(mc.x, j + 2);
        int w2 = __builtin_amdgcn_readlane(mc.y, j + 2);
        int s3 = __builtin_amdgcn_readlane(mc.x, j + 3);
        int w3 = __builtin_amdgcn_readlane(mc.y, j + 3);
        int s4 = __builtin_amdgcn_readlane(mc.x, j + 4);
        int w4 = __builtin_amdgcn_readlane(mc.y, j + 4);
        int s5 = __builtin_amdgcn_readlane(mc.x, j + 5);
        int w5 = __builtin_amdgcn_readlane(mc.y, j + 5);
        int s6 = __builtin_amdgcn_readlane(mc.x, j + 6);
        int w6 = __builtin_amdgcn_readlane(mc.y, j + 6);
        int s7 = __builtin_amdgcn_readlane(mc.x, j + 7);
        int w7 = __builtin_amdgcn_readlane(mc.y, j + 7);
        float v0 = hp[(size_t)s0 * 64 + lane];
        float v1 = hp[(size_t)s1 * 64 + lane];
        float v2 = hp[(size_t)s2 * 64 + lane];
        float v3 = hp[(size_t)s3 * 64 + lane];
        float v4 = hp[(size_t)s4 * 64 + lane];
        float v5 = hp[(size_t)s5 * 64 + lane];
        float v6 = hp[(size_t)s6 * 64 + lane];
        float v7 = hp[(size_t)s7 * 64 + lane];
        a0 = fmaf(v0, __int_as_float(w0), a0);
        a1 = fmaf(v1, __int_as_float(w1), a1);
        a2 = fmaf(v2, __int_as_float(w2), a2);
        a3 = fmaf(v3, __int_as_float(w3), a3);
        a4 = fmaf(v4, __int_as_float(w4), a4);
        a5 = fmaf(v5, __int_as_float(w5), a5);
        a6 = fmaf(v6, __int_as_float(w6), a6);
        a7 = fmaf(v7, __int_as_float(w7), a7);
    }
    // rare overflow (deg > 64)
    for (int j = 64; j < c; ++j) {
        int2 e = csr[s + j];
        a0 = fmaf(hp[(size_t)e.x * 64 + lane], __int_as_float(e.y), a0);
    }
    float r = (((a0 + a1) + (a2 + a3)) + ((a4 + a5) + (a6 + a7)));
    float o = fmaf(r, dinv[node], bias[lane]);
    out[(size_t)node * 64 + lane] = fmaxf(o, 0.0f);
}

// --- mean pool per graph + fused MLP head ------------------------------------
__global__ __launch_bounds__(1024) void k_pool_head(
    const float* __restrict__ h, const int* __restrict__ batch, int n,
    const float* __restrict__ Wc1, const float* __restrict__ bc1,
    const float* __restrict__ Wc2, const float* __restrict__ bc2,
    float* __restrict__ out) {
    const int g = blockIdx.x;
    const int t = threadIdx.x;
    const int lane = t & 63, w = t >> 6;   // 16 waves
    __shared__ float sums[16][64];
    __shared__ float pooled[64];
    __shared__ float z[32];

    int start = lower_bound_i(batch, n, g);
    int end   = lower_bound_i(batch, n, g + 1);

    float acc = 0.f;
    for (int i = start + w; i < end; i += 16)
        acc += h[(size_t)i * 64 + lane];
    sums[w][lane] = acc;
    __syncthreads();
    if (w == 0) {
        float v = 0.f;
#pragma unroll
        for (int k = 0; k < 16; k++) v += sums[k][lane];
        float c = (float)(end - start);
        pooled[lane] = v / fmaxf(c, 1.0f);
    }
    __syncthreads();
    if (t < 32) {
        float a = bc1[t];
        for (int k = 0; k < 64; k++) a = fmaf(pooled[k], Wc1[k * 32 + t], a);
        z[t] = fmaxf(a, 0.f);
    }
    __syncthreads();
    if (t < 10) {
        float a = bc2[t];
        for (int k = 0; k < 32; k++) a = fmaf(z[k], Wc2[k * 10 + t], a);
        out[g * 10 + t] = a;
    }
}

// ---------------------------------------------------------------------------
extern "C" void kernel_launch(void* const* d_in, const int* in_sizes, int n_in,
                              void* d_out, int out_size, void* d_ws, size_t ws_size,
                              hipStream_t stream) {
    const float* x    = (const float*)d_in[0];
    const int*   ei   = (const int*)d_in[1];
    const float* ew   = (const float*)d_in[2];
    const int*   bat  = (const int*)d_in[3];
    const float* W1   = (const float*)d_in[4];
    const float* b1   = (const float*)d_in[5];
    const float* W2   = (const float*)d_in[6];
    const float* b2   = (const float*)d_in[7];
    const float* Wc1  = (const float*)d_in[8];
    const float* bc1  = (const float*)d_in[9];
    const float* Wc2  = (const float*)d_in[10];
    const float* bc2  = (const float*)d_in[11];
    float* out = (float*)d_out;

    const int N = in_sizes[0] / 128;
    const int E = in_sizes[2];
    const int G = out_size / 10;
    const int K = (N + 255) >> BKT_BITS;          // buckets of 256 nodes
    const int KB = K * PART_BLOCKS;               // histogram elements
    const int CH = (E + PART_BLOCKS - 1) / PART_BLOCKS;  // edges per partition block

    const int* row = ei;
    const int* col = ei + E;

    // workspace carve-up (256B aligned slices)
    char* p = (char*)d_ws;
    auto alloc = [&](size_t bytes) -> void* {
        void* r = (void*)p;
        p += (bytes + 255) & ~(size_t)255;
        return r;
    };
    int*   bh    = (int*)  alloc((size_t)KB * 4);
    int*   bhs   = (int*)  alloc((size_t)KB * 4);
    int*   bsums = (int*)  alloc(8192);
    int*   offs  = (int*)  alloc((size_t)N * 4);
    int*   cnt   = (int*)  alloc((size_t)N * 4);
    float* dinv  = (float*)alloc((size_t)N * 4);
    int2*  csr   = (int2*) alloc((size_t)E * 8);
    // h aliases the partition arrays (part2/partc dead before matmul1 runs)
    char*  hbase = (char*) alloc((size_t)N * 64 * 4 > (size_t)E * 12 ? (size_t)N * 64 * 4
                                                                     : (size_t)E * 12);
    float* o     = (float*)alloc((size_t)N * 64 * 4);
    int2*  part2 = (int2*) hbase;
    int*   partc = (int*)  (hbase + (size_t)E * 8);
    float* h     = (float*)hbase;

    const int NB = (KB + 1023) / 1024;

    // CSR build: zero global atomics
    k_histA<<<PART_BLOCKS, 256, 0, stream>>>(col, E, CH, K, bh);
    k_scan_partial<<<NB, TPB, 0, stream>>>(bh, bsums, KB);
    k_scan_bsums<<<1, 64, 0, stream>>>(bsums, NB);
    k_scan_final<<<NB, TPB, 0, stream>>>(bh, bsums, bhs, KB);
    k_partB<<<PART_BLOCKS, 256, 0, stream>>>(row, col, ew, bhs, E, CH, K, part2, partc);
    k_csrC<<<K, 256, 0, stream>>>(part2, partc, bhs, K, N, E, offs, cnt, dinv, csr);

    const int gb_mm = (N + 63) / 64;
    const int gb_ag = (N + 3) / 4;

    // layer 1
    k_matmul<128><<<gb_mm, 256, 0, stream>>>(x, W1, dinv, h, N);
    k_aggregate<<<gb_ag, 256, 0, stream>>>(h, offs, cnt, csr, dinv, b1, o, N);
    // layer 2
    k_matmul<64><<<gb_mm, 256, 0, stream>>>(o, W2, dinv, h, N);
    k_aggregate<<<gb_ag, 256, 0, stream>>>(h, offs, cnt, csr, dinv, b2, o, N);
    // pool + head
    k_pool_head<<<G, 1024, 0, stream>>>(o, bat, N, Wc1, bc1, Wc2, bc2, out);
}